// Round 8
// baseline (35.474 us; speedup 1.0000x reference)
//
#include <hip/hip_runtime.h>
#include <math.h>

// B=8, F=128, K=256, E=256, alpha=0.2
#define BB 8
#define FF 128
#define KK 256
#define EE 256
#define TI 4

typedef float f4 __attribute__((ext_vector_type(4)));
typedef float f2 __attribute__((ext_vector_type(2)));

__device__ __forceinline__ float rdl(float v, int l) {
  return __int_as_float(__builtin_amdgcn_readlane(__float_as_int(v), l));
}

// Force a wave-uniform pointer into SGPRs -> scalar-path (s_load) loads.
__device__ __forceinline__ const float* uni(const float* ptr) {
  uintptr_t v = (uintptr_t)ptr;
  uint32_t lo = __builtin_amdgcn_readfirstlane((uint32_t)v);
  uint32_t hi = __builtin_amdgcn_readfirstlane((uint32_t)(v >> 32));
  return (const float*)(((uintptr_t)hi << 32) | lo);
}

// ---------------------------------------------------------------------------
// prep: p[b][k][e] = sum_f x[b,f,k] W[f,e] + b_lin[e]   (row-major, 2MB)
//       qT[b][e][k] = sum_f x[b,f,k] W[F+f,e]           (transposed, 2MB)
//       xT[b][k][f] = x[b][f][k]                        (1MB)
//       Q6[b][k]    = 0.6 * sum_e a[e]*q[b][k][e]       (8KB)
// grid 256 blocks, blockIdx = kt*8 + b (XCD-pinned: XCD = b) x 512 threads
// ---------------------------------------------------------------------------
__global__ __launch_bounds__(512, 2) void prep_kernel(
    const float* __restrict__ x, const float* __restrict__ W,
    const float* __restrict__ b_lin, const float* __restrict__ a,
    float* __restrict__ p, float* __restrict__ qT,
    float* __restrict__ xT, float* __restrict__ Q6) {
  __shared__ float xs[FF][8];
  __shared__ float part[16][EE];

  const int b  = blockIdx.x & 7;          // XCD = blockIdx % 8 = b
  const int k0 = (blockIdx.x >> 3) * 8;
  const int t  = threadIdx.x;

  {
    const float* xb = x + b * FF * KK + k0;
    const int f = t >> 3, u = t & 7;
    xs[f][u]      = xb[f * KK + u];
    xs[f + 64][u] = xb[(f + 64) * KK + u];
  }
  __syncthreads();

  {
    const int u = t >> 6, f2i = (t & 63) * 2;
    f2 v; v.x = xs[f2i][u]; v.y = xs[f2i + 1][u];
    *(f2*)&xT[(b * KK + k0 + u) * FF + f2i] = v;
  }

  const int e = t & 255, fh = t >> 8;
  float pacc[8] = {0,0,0,0,0,0,0,0}, qacc[8] = {0,0,0,0,0,0,0,0};
  {
    const float* Wp = W + (fh * 64) * EE + e;
    const float* Wq = W + (FF + fh * 64) * EE + e;
    const float* xr = &xs[fh * 64][0];
#pragma unroll 8
    for (int ff = 0; ff < 64; ++ff) {
      const float w1 = Wp[ff * EE];
      const float w2 = Wq[ff * EE];
      const f4 xv0 = *(const f4*)(xr + ff * 8);
      const f4 xv1 = *(const f4*)(xr + ff * 8 + 4);
#pragma unroll
      for (int u = 0; u < 4; ++u) {
        pacc[u]     = fmaf(xv0[u], w1, pacc[u]);
        qacc[u]     = fmaf(xv0[u], w2, qacc[u]);
        pacc[4 + u] = fmaf(xv1[u], w1, pacc[4 + u]);
        qacc[4 + u] = fmaf(xv1[u], w2, qacc[4 + u]);
      }
    }
  }

  if (fh == 1) {
#pragma unroll
    for (int u = 0; u < 8; ++u) { part[u][e] = pacc[u]; part[8 + u][e] = qacc[u]; }
  }
  __syncthreads();
  if (fh == 0) {
    const float bl = b_lin[e], ae = a[e];
#pragma unroll
    for (int u = 0; u < 8; ++u) {
      const float pv = pacc[u] + part[u][e] + bl;
      const float qv = qacc[u] + part[8 + u][e];
      p[(b * KK + k0 + u) * EE + e] = pv;
      part[u][e]     = ae * qv;
      part[8 + u][e] = qv;
    }
  }
  __syncthreads();

  {
    const int ee = t >> 1, k4 = (t & 1) * 4;
    f4 v;
#pragma unroll
    for (int u = 0; u < 4; ++u) v[u] = part[8 + k4 + u][ee];
    *(f4*)&qT[(b * EE + ee) * KK + k0 + k4] = v;
  }

  {
    const int w = t >> 6, lane = t & 63;
    float s = part[w][lane] + part[w][lane + 64] + part[w][lane + 128] + part[w][lane + 192];
#pragma unroll
    for (int off = 32; off; off >>= 1) s += __shfl_xor(s, off, 64);
    if (lane == 0) Q6[b * KK + k0 + w] = 0.6f * s;
  }
}

// ---------------------------------------------------------------------------
// attn v5: grid 512, blockIdx = it*8 + b (XCD-pinned), 512 threads (8 waves).
// P1: wave (eq, jh): e in [64eq,+64), j = jh*128 + 2*lane + {0,1}, all 4 i.
//     p/a read via SCALAR path (readfirstlane-forced s_load) -> LDS pipe idle.
// P2: waves 0..3: softmax row i=w, 4-partial reduce fused.
// P3: wave w: j-window [32w,+32), all 4 i, f = 2*lane+{0,1}; readlane bcast.
// LDS 36.5KB.
// ---------------------------------------------------------------------------
__global__ __launch_bounds__(512, 4) void attn_kernel(
    const float* __restrict__ p, const float* __restrict__ qT,
    const float* __restrict__ xT, const float* __restrict__ Q6,
    const float* __restrict__ a, const float* __restrict__ bias,
    float* __restrict__ out) {
  __shared__ float red[4][TI][KK];     // 16KB e-quarter partials
  __shared__ float sc[TI][KK];         // 4KB attn weights
  __shared__ float pvp[8][TI][132];    // 16.5KB PV partials (padded)

  const int b    = blockIdx.x & 7;     // XCD = b
  const int i0   = (blockIdx.x >> 3) * TI;
  const int t    = threadIdx.x;
  const int w    = t >> 6;
  const int lane = t & 63;

  // ---- phase 1: partial scores; p/a on scalar path, qT per-lane stream ----
  {
    const int eq = w >> 1, jh = w & 1;
    const int e0 = eq * 64;
    const float* pb = uni(p + (b * KK + i0) * EE + e0);  // SGPR base
    const float* ab = uni(a + e0);                       // SGPR base
    f2 acc[TI];
#pragma unroll
    for (int i = 0; i < TI; ++i) acc[i] = (f2){0.f, 0.f};
    const float* qc = qT + (b * EE + e0) * KK + jh * 128 + 2 * lane;
#pragma unroll 4
    for (int c = 0; c < 16; ++c) {
      const f2 q0 = *(const f2*)(qc);            // 8B/lane coalesced
      const f2 q1 = *(const f2*)(qc + KK);       // imm offsets 1/2/3KB
      const f2 q2 = *(const f2*)(qc + 2 * KK);
      const f2 q3 = *(const f2*)(qc + 3 * KK);
      const f4 av = *(const f4*)(ab + 4 * c);    // s_load_dwordx4
#pragma unroll
      for (int i = 0; i < TI; ++i) {
        const f4 pv = *(const f4*)(pb + i * EE + 4 * c);  // s_load_dwordx4
        acc[i].x = fmaf(fabsf(q0.x + pv[0]), av[0], acc[i].x);  // abs = VOP3 mod
        acc[i].y = fmaf(fabsf(q0.y + pv[0]), av[0], acc[i].y);
        acc[i].x = fmaf(fabsf(q1.x + pv[1]), av[1], acc[i].x);
        acc[i].y = fmaf(fabsf(q1.y + pv[1]), av[1], acc[i].y);
        acc[i].x = fmaf(fabsf(q2.x + pv[2]), av[2], acc[i].x);
        acc[i].y = fmaf(fabsf(q2.y + pv[2]), av[2], acc[i].y);
        acc[i].x = fmaf(fabsf(q3.x + pv[3]), av[3], acc[i].x);
        acc[i].y = fmaf(fabsf(q3.y + pv[3]), av[3], acc[i].y);
      }
      qc += 4 * KK;
    }
    const int jb = jh * 128 + 2 * lane;
#pragma unroll
    for (int i = 0; i < TI; ++i)
      *(f2*)&red[w >> 1][i][jb] = acc[i];        // b64, conflict-free
  }
  __syncthreads();

  // ---- phase 2: softmax rows (waves 0..3, row i=w), reduce fused ----
  if (w < TI) {
    const int i = w;
    f4 s = (f4){0.f, 0.f, 0.f, 0.f};
#pragma unroll
    for (int eq = 0; eq < 4; ++eq)
      s += *(const f4*)&red[eq][i][4 * lane];
    const f4 q6 = *(const f4*)&Q6[b * KK + 4 * lane];
    const f4 bv = *(const f4*)&bias[(i0 + i) * KK + 4 * lane];
    f4 ev;
#pragma unroll
    for (int v = 0; v < 4; ++v)
      ev[v] = __expf(0.4f * s[v] + q6[v] + bv[v]);  // |score| < ~10: exp safe
    float tot = ev[0] + ev[1] + ev[2] + ev[3];
#pragma unroll
    for (int off = 32; off; off >>= 1) tot += __shfl_xor(tot, off, 64);
    const float inv = 1.f / tot;
#pragma unroll
    for (int v = 0; v < 4; ++v) ev[v] *= inv;
    *(f4*)&sc[i][4 * lane] = ev;
  }
  __syncthreads();

  // ---- phase 3: PV. wave w: j in [32w,+32), all 4 i, f = 2*lane+{0,1} ----
  {
    const int j0 = 32 * w;
    float rv[TI];
#pragma unroll
    for (int i = 0; i < TI; ++i) rv[i] = sc[i][j0 + (lane & 31)];  // 2-way, free
    f2 pacc[TI];
#pragma unroll
    for (int i = 0; i < TI; ++i) pacc[i] = (f2){0.f, 0.f};
    const float* xb = xT + (b * KK + j0) * FF + 2 * lane;
#pragma unroll 4
    for (int jj = 0; jj < 32; ++jj) {
      const f2 xv = *(const f2*)(xb + jj * FF);   // 8B/lane coalesced, L2-hot
#pragma unroll
      for (int i = 0; i < TI; ++i) {
        const float sv = rdl(rv[i], jj);          // SGPR-index readlane (VALU)
        pacc[i].x = fmaf(sv, xv.x, pacc[i].x);
        pacc[i].y = fmaf(sv, xv.y, pacc[i].y);
      }
    }
#pragma unroll
    for (int i = 0; i < TI; ++i)
      *(f2*)&pvp[w][i][2 * lane] = pacc[i];
  }
  __syncthreads();

  // ---- combine 8 j-windows + sigmoid + store ----
  {
    const int f = t >> 2, i = t & 3;
    float s = 0.f;
#pragma unroll
    for (int jo = 0; jo < 8; ++jo) s += pvp[jo][i][f];
    out[(b * FF + f) * KK + i0 + i] = 1.f / (1.f + __expf(-s));
  }
}

extern "C" void kernel_launch(void* const* d_in, const int* in_sizes, int n_in,
                              void* d_out, int out_size, void* d_ws, size_t ws_size,
                              hipStream_t stream) {
  const float* x     = (const float*)d_in[0];
  const float* W     = (const float*)d_in[1];
  const float* b_lin = (const float*)d_in[2];
  const float* a     = (const float*)d_in[3];
  const float* bias  = (const float*)d_in[4];
  float* out = (float*)d_out;

  float* p  = (float*)d_ws;                    // [B,K,E] 2MB
  float* qT = p  + BB * KK * EE;               // [B,E,K] 2MB
  float* xT = qT + BB * EE * KK;               // [B,K,F] 1MB
  float* Q6 = xT + BB * KK * FF;               // [B,K]   8KB

  prep_kernel<<<(KK / 8) * 8, 512, 0, stream>>>(x, W, b_lin, a, p, qT, xT, Q6);
  attn_kernel<<<(KK / TI) * 8, 512, 0, stream>>>(p, qT, xT, Q6, a, bias, out);
}

// Round 9
// 27.139 us; speedup vs baseline: 1.3071x; 1.3071x over previous
//
#include <hip/hip_runtime.h>
#include <math.h>

// B=8, F=128, K=256, E=256, alpha=0.2
#define BB 8
#define FF 128
#define KK 256
#define EE 256
#define TI 4

typedef float f4 __attribute__((ext_vector_type(4)));
typedef float f2 __attribute__((ext_vector_type(2)));

__device__ __forceinline__ float rdl(float v, int l) {
  return __int_as_float(__builtin_amdgcn_readlane(__float_as_int(v), l));
}

// ---------------------------------------------------------------------------
// prep: p[b][k][e] = sum_f x[b,f,k] W[f,e] + b_lin[e]   (row-major, 2MB)
//       qT[b][e][k] = sum_f x[b,f,k] W[F+f,e]           (transposed, 2MB)
//       xT[b][k][f] = x[b][f][k]                        (1MB)
//       Q6[b][k]    = 0.6 * sum_e a[e]*q[b][k][e]       (8KB)
// grid 256 blocks, blockIdx = kt*8 + b (XCD-pinned: XCD = b) x 512 threads
// ---------------------------------------------------------------------------
__global__ __launch_bounds__(512, 2) void prep_kernel(
    const float* __restrict__ x, const float* __restrict__ W,
    const float* __restrict__ b_lin, const float* __restrict__ a,
    float* __restrict__ p, float* __restrict__ qT,
    float* __restrict__ xT, float* __restrict__ Q6) {
  __shared__ float xs[FF][8];
  __shared__ float part[16][EE];

  const int b  = blockIdx.x & 7;          // XCD = blockIdx % 8 = b
  const int k0 = (blockIdx.x >> 3) * 8;
  const int t  = threadIdx.x;

  {
    const float* xb = x + b * FF * KK + k0;
    const int f = t >> 3, u = t & 7;
    xs[f][u]      = xb[f * KK + u];
    xs[f + 64][u] = xb[(f + 64) * KK + u];
  }
  __syncthreads();

  {
    const int u = t >> 6, f2i = (t & 63) * 2;
    f2 v; v.x = xs[f2i][u]; v.y = xs[f2i + 1][u];
    *(f2*)&xT[(b * KK + k0 + u) * FF + f2i] = v;
  }

  const int e = t & 255, fh = t >> 8;
  float pacc[8] = {0,0,0,0,0,0,0,0}, qacc[8] = {0,0,0,0,0,0,0,0};
  {
    const float* Wp = W + (fh * 64) * EE + e;
    const float* Wq = W + (FF + fh * 64) * EE + e;
    const float* xr = &xs[fh * 64][0];
#pragma unroll 8
    for (int ff = 0; ff < 64; ++ff) {
      const float w1 = Wp[ff * EE];
      const float w2 = Wq[ff * EE];
      const f4 xv0 = *(const f4*)(xr + ff * 8);
      const f4 xv1 = *(const f4*)(xr + ff * 8 + 4);
#pragma unroll
      for (int u = 0; u < 4; ++u) {
        pacc[u]     = fmaf(xv0[u], w1, pacc[u]);
        qacc[u]     = fmaf(xv0[u], w2, qacc[u]);
        pacc[4 + u] = fmaf(xv1[u], w1, pacc[4 + u]);
        qacc[4 + u] = fmaf(xv1[u], w2, qacc[4 + u]);
      }
    }
  }

  if (fh == 1) {
#pragma unroll
    for (int u = 0; u < 8; ++u) { part[u][e] = pacc[u]; part[8 + u][e] = qacc[u]; }
  }
  __syncthreads();
  if (fh == 0) {
    const float bl = b_lin[e], ae = a[e];
#pragma unroll
    for (int u = 0; u < 8; ++u) {
      const float pv = pacc[u] + part[u][e] + bl;
      const float qv = qacc[u] + part[8 + u][e];
      p[(b * KK + k0 + u) * EE + e] = pv;
      part[u][e]     = ae * qv;
      part[8 + u][e] = qv;
    }
  }
  __syncthreads();

  {
    const int ee = t >> 1, k4 = (t & 1) * 4;
    f4 v;
#pragma unroll
    for (int u = 0; u < 4; ++u) v[u] = part[8 + k4 + u][ee];
    *(f4*)&qT[(b * EE + ee) * KK + k0 + k4] = v;
  }

  {
    const int w = t >> 6, lane = t & 63;
    float s = part[w][lane] + part[w][lane + 64] + part[w][lane + 128] + part[w][lane + 192];
#pragma unroll
    for (int off = 32; off; off >>= 1) s += __shfl_xor(s, off, 64);
    if (lane == 0) Q6[b * KK + k0 + w] = 0.6f * s;
  }
}

// ---------------------------------------------------------------------------
// attn v6: grid 512, blockIdx = it*8 + b (XCD-pinned), 512 threads (8 waves).
// = round-7 structure (best known) + explicit load/compute rotation:
// P1: preload chunk-0 q's BEFORE the staging barrier; each iter loads c+1
//     while computing c. P3: first x-load hoisted above softmax; rotation.
// LDS pt/a_s broadcasts (NOT s_load - r8 showed that regresses).
// ---------------------------------------------------------------------------
__global__ __launch_bounds__(512, 4) void attn_kernel(
    const float* __restrict__ p, const float* __restrict__ qT,
    const float* __restrict__ xT, const float* __restrict__ Q6,
    const float* __restrict__ a, const float* __restrict__ bias,
    float* __restrict__ out) {
  __shared__ float pt[TI][EE];         // 4KB
  __shared__ float a_s[EE];            // 1KB
  __shared__ float red[4][TI][KK];     // 16KB e-quarter partials
  __shared__ float sc[TI][KK];         // 4KB attn weights
  __shared__ float pvp[8][TI][132];    // 16.5KB PV partials (padded)

  const int b    = blockIdx.x & 7;     // XCD = b
  const int i0   = (blockIdx.x >> 3) * TI;
  const int t    = threadIdx.x;
  const int w    = t >> 6;
  const int lane = t & 63;

  // ---- phase 0: stage p-tile + a ----
  if (t < 256) {
    const int i = t >> 6, e4 = (t & 63) * 4;
    *(f4*)&pt[i][e4] = *(const f4*)&p[(b * KK + i0 + i) * EE + e4];
  } else if (t < 320) {
    const int e4 = (t - 256) * 4;
    *(f4*)&a_s[e4] = *(const f4*)&a[e4];
  }

  // ---- phase 1 prologue: preload chunk 0 (global, barrier-independent) ----
  const int eq = w >> 1, jh = w & 1;
  const int e0 = eq * 64;
  const float* qc = qT + (b * EE + e0) * KK + jh * 128 + 2 * lane;
  f2 q0 = *(const f2*)(qc);
  f2 q1 = *(const f2*)(qc + KK);
  f2 q2 = *(const f2*)(qc + 2 * KK);
  f2 q3 = *(const f2*)(qc + 3 * KK);
  qc += 4 * KK;
  __syncthreads();

  // ---- phase 1: rotation pipeline (load c+1 while computing c) ----
  {
    f2 acc[TI];
#pragma unroll
    for (int i = 0; i < TI; ++i) acc[i] = (f2){0.f, 0.f};
#pragma unroll 4
    for (int c = 0; c < 16; ++c) {
      // next-chunk loads (c=15 overreads 1KB into the next ws region: benign)
      const f2 n0 = *(const f2*)(qc);
      const f2 n1 = *(const f2*)(qc + KK);
      const f2 n2 = *(const f2*)(qc + 2 * KK);
      const f2 n3 = *(const f2*)(qc + 3 * KK);
      qc += 4 * KK;
      const f4 av = *(const f4*)&a_s[e0 + 4 * c];      // uniform LDS b128
#pragma unroll
      for (int i = 0; i < TI; ++i) {
        const f4 pv = *(const f4*)&pt[i][e0 + 4 * c];  // uniform LDS b128
        acc[i].x = fmaf(fabsf(q0.x + pv[0]), av[0], acc[i].x);  // abs = VOP3 mod
        acc[i].y = fmaf(fabsf(q0.y + pv[0]), av[0], acc[i].y);
        acc[i].x = fmaf(fabsf(q1.x + pv[1]), av[1], acc[i].x);
        acc[i].y = fmaf(fabsf(q1.y + pv[1]), av[1], acc[i].y);
        acc[i].x = fmaf(fabsf(q2.x + pv[2]), av[2], acc[i].x);
        acc[i].y = fmaf(fabsf(q2.y + pv[2]), av[2], acc[i].y);
        acc[i].x = fmaf(fabsf(q3.x + pv[3]), av[3], acc[i].x);
        acc[i].y = fmaf(fabsf(q3.y + pv[3]), av[3], acc[i].y);
      }
      q0 = n0; q1 = n1; q2 = n2; q3 = n3;
    }
    const int jb = jh * 128 + 2 * lane;
#pragma unroll
    for (int i = 0; i < TI; ++i)
      *(f2*)&red[eq][i][jb] = acc[i];        // b64, conflict-free
  }
  __syncthreads();

  // ---- phase 3 prologue: first x-load in flight during softmax ----
  const int j0 = 32 * w;
  const float* xb = xT + (b * KK + j0) * FF + 2 * lane;
  f2 xv = *(const f2*)(xb);

  // ---- phase 2: softmax rows (waves 0..3, row i=w), reduce fused ----
  if (w < TI) {
    const int i = w;
    f4 s = (f4){0.f, 0.f, 0.f, 0.f};
#pragma unroll
    for (int e8 = 0; e8 < 4; ++e8)
      s += *(const f4*)&red[e8][i][4 * lane];
    const f4 q6 = *(const f4*)&Q6[b * KK + 4 * lane];
    const f4 bv = *(const f4*)&bias[(i0 + i) * KK + 4 * lane];
    f4 ev;
#pragma unroll
    for (int v = 0; v < 4; ++v)
      ev[v] = __expf(0.4f * s[v] + q6[v] + bv[v]);  // |score| < ~10: exp safe
    float tot = ev[0] + ev[1] + ev[2] + ev[3];
#pragma unroll
    for (int off = 32; off; off >>= 1) tot += __shfl_xor(tot, off, 64);
    const float inv = 1.f / tot;
#pragma unroll
    for (int v = 0; v < 4; ++v) ev[v] *= inv;
    *(f4*)&sc[i][4 * lane] = ev;
  }
  __syncthreads();

  // ---- phase 3: PV with rotation. wave w: j in [32w,+32), f = 2*lane+{0,1} ----
  {
    float rv[TI];
#pragma unroll
    for (int i = 0; i < TI; ++i) rv[i] = sc[i][j0 + (lane & 31)];  // 2-way, free
    f2 pacc[TI];
#pragma unroll
    for (int i = 0; i < TI; ++i) pacc[i] = (f2){0.f, 0.f};
#pragma unroll 4
    for (int jj = 0; jj < 32; ++jj) {
      const f2 nx = *(const f2*)(xb + (jj + 1) * FF);  // next (last overreads: benign)
#pragma unroll
      for (int i = 0; i < TI; ++i) {
        const float sv = rdl(rv[i], jj);          // SGPR-index readlane (VALU)
        pacc[i].x = fmaf(sv, xv.x, pacc[i].x);
        pacc[i].y = fmaf(sv, xv.y, pacc[i].y);
      }
      xv = nx;
    }
#pragma unroll
    for (int i = 0; i < TI; ++i)
      *(f2*)&pvp[w][i][2 * lane] = pacc[i];
  }
  __syncthreads();

  // ---- combine 8 j-windows + sigmoid + store ----
  {
    const int f = t >> 2, i = t & 3;
    float s = 0.f;
#pragma unroll
    for (int jo = 0; jo < 8; ++jo) s += pvp[jo][i][f];
    out[(b * FF + f) * KK + i0 + i] = 1.f / (1.f + __expf(-s));
  }
}

extern "C" void kernel_launch(void* const* d_in, const int* in_sizes, int n_in,
                              void* d_out, int out_size, void* d_ws, size_t ws_size,
                              hipStream_t stream) {
  const float* x     = (const float*)d_in[0];
  const float* W     = (const float*)d_in[1];
  const float* b_lin = (const float*)d_in[2];
  const float* a     = (const float*)d_in[3];
  const float* bias  = (const float*)d_in[4];
  float* out = (float*)d_out;

  float* p  = (float*)d_ws;                    // [B,K,E] 2MB
  float* qT = p  + BB * KK * EE;               // [B,E,K] 2MB
  float* xT = qT + BB * EE * KK;               // [B,K,F] 1MB
  float* Q6 = xT + BB * KK * FF;               // [B,K]   8KB

  prep_kernel<<<(KK / 8) * 8, 512, 0, stream>>>(x, W, b_lin, a, p, qT, xT, Q6);
  attn_kernel<<<(KK / TI) * 8, 512, 0, stream>>>(p, qT, xT, Q6, a, bias, out);
}